// Round 8
// baseline (282.697 us; speedup 1.0000x reference)
//
#include <hip/hip_runtime.h>
#include <hip/hip_bf16.h>
#include <cstdint>

// LocalRNN: B=16 L=1024 D=256 H=256 K=16 (GRU over K-window per position).
// FP32 in/out. Round-8: 1024-thr blocks, 16 waves x 16-col hidden stripes.
//   wf (W_hh frags) = 96 regs/wave -> fits 128-reg budget for 4 waves/SIMD
//   (2x occupancy vs r7's 192-reg waves). gi GEMM reads x direct from global;
//   h-old read from LDS double buffer; one barrier/step; exp2-folded gates.

#define B_  16
#define L_  1024
#define D_  256
#define H_  256
#define K_  16
#define MT  32             // positions per block
#define NROW 47            // gi rows per block = MT + K - 1
#define HS  264            // h LDS row stride (u16)
#define GRS 258            // grz LDS row stride (u32)
#define GNS 264            // gn LDS row stride (u16)
#define L2E 1.44269504f
#define NWR 196608         // 768*256

typedef __attribute__((ext_vector_type(8))) short  bf16x8;
typedef __attribute__((ext_vector_type(4))) float  floatx4;
typedef unsigned short ush;

#if __has_builtin(__builtin_amdgcn_exp2f)
#define fexp2(x) __builtin_amdgcn_exp2f(x)
#else
#define fexp2(x) exp2f(x)
#endif

__device__ __forceinline__ float bf2f(ush u) {
    union { unsigned int i; float f; } v; v.i = ((unsigned int)u) << 16; return v.f;
}
__device__ __forceinline__ ush f2bf(float f) {
    union { float f; unsigned int i; } v; v.f = f;
    unsigned int x = v.i;
    return (ush)((x + 0x7FFFu + ((x >> 16) & 1u)) >> 16);  // RNE
}
__device__ __forceinline__ unsigned int pk2(float a, float b) {
    union { __hip_bfloat162 v; unsigned int u; } c;
    c.v = __float22bfloat162_rn(make_float2(a, b));  // lo=a, hi=b
    return c.u;
}
__device__ __forceinline__ float rcpf(float x) { return __builtin_amdgcn_rcpf(x); }

// ---- wprep: repack W_ih / W_hh into 16-wave frag layout, scale-folded ------
// element e = (w*24 + g*8 + ks)*512 + lane*8 + j ; wave w owns cols w*16..+15
__global__ __launch_bounds__(256) void wprep(const float* __restrict__ Wih,
                                             const float* __restrict__ Whh,
                                             ush* __restrict__ Wir,
                                             ush* __restrict__ Wr) {
    int idx = blockIdx.x * 256 + threadIdx.x;       // 0 .. 2*NWR-1
    const float* src = (idx < NWR) ? Whh : Wih;
    ush* dst         = (idx < NWR) ? Wr  : Wir;
    int e = (idx < NWR) ? idx : idx - NWR;
    int w  = e / 12288, r1 = e % 12288;
    int f  = r1 / 512,  r3 = r1 % 512;              // f = g*8 + ks
    int g  = f >> 3,    ks = f & 7;
    int lane = r3 >> 3, j  = r3 & 7;
    int l16 = lane & 15, quad = lane >> 4;
    int srow = g * 256 + w * 16 + l16;
    int scol = ks * 32 + quad * 8 + j;
    float scl = (g < 2) ? -L2E : 2.f * L2E;
    dst[e] = f2bf(src[srow * 256 + scol] * scl);
}

// ---- fused kernel: 512 blocks x 1024 thr -----------------------------------
__global__ __launch_bounds__(1024) void rnn_fused(const float* __restrict__ x,
                                                  const ush* __restrict__ Wir,
                                                  const ush* __restrict__ Wr,
                                                  const float* __restrict__ bih,
                                                  const float* __restrict__ bhh,
                                                  float* __restrict__ out) {
    __shared__ unsigned int grz[NROW * GRS];        // 48,504 B
    __shared__ __align__(16) ush gn[NROW * GNS];    // 24,816 B
    __shared__ __align__(16) ush hl[2][MT * HS];    // 33,792 B  (tot 107,112)

    int tid  = threadIdx.x;
    int wave = tid >> 6, lane = tid & 63;
    int l16  = lane & 15, quad = lane >> 4, quad4 = quad * 4;
    int p0   = blockIdx.x * MT;
    int bb   = p0 >> 10, lb = p0 & 1023;
    int col  = wave * 16 + l16;                     // this thread's hidden col

    // ---- zero h[0] ---------------------------------------------------------
    for (int idx = tid; idx < MT * HS / 2; idx += 1024)
        ((unsigned int*)(&hl[0][0]))[idx] = 0u;

    // ---- phase 1: gi GEMM (A direct from global x, fp32->bf16 in regs) -----
    {
        floatx4 g0[3], g1[3], g2[3];                // [mt], gates r,z,n
        float br = -L2E * (bih[col] + bhh[col]);
        float bz = -L2E * (bih[256 + col] + bhh[256 + col]);
        float bn_ = 2.f * L2E * bih[512 + col];
#pragma unroll
        for (int mt = 0; mt < 3; mt++) {
            g0[mt] = (floatx4){br, br, br, br};
            g1[mt] = (floatx4){bz, bz, bz, bz};
            g2[mt] = (floatx4){bn_, bn_, bn_, bn_};
        }
        const float* xrow[3];
        bool vld[3];
#pragma unroll
        for (int mt = 0; mt < 3; mt++) {
            int tok = lb - 15 + mt * 16 + l16;
            vld[mt]  = (unsigned)tok < (unsigned)L_;
            xrow[mt] = x + ((size_t)((bb << 10) + (vld[mt] ? tok : 0))) * D_ + quad * 8;
        }
        const ush* wp = Wir + (size_t)wave * 12288 + lane * 8;
#pragma unroll
        for (int ks = 0; ks < 8; ks++) {
            bf16x8 bw0 = *(const bf16x8*)(wp + ((0 * 8 + ks) << 9));
            bf16x8 bw1 = *(const bf16x8*)(wp + ((1 * 8 + ks) << 9));
            bf16x8 bw2 = *(const bf16x8*)(wp + ((2 * 8 + ks) << 9));
#pragma unroll
            for (int mt = 0; mt < 3; mt++) {
                union { uint4 u; bf16x8 v; } af;
                if (vld[mt]) {
                    float4 a0 = *(const float4*)(xrow[mt] + ks * 32);
                    float4 a1 = *(const float4*)(xrow[mt] + ks * 32 + 4);
                    af.u = make_uint4(pk2(a0.x, a0.y), pk2(a0.z, a0.w),
                                      pk2(a1.x, a1.y), pk2(a1.z, a1.w));
                } else {
                    af.u = make_uint4(0u, 0u, 0u, 0u);
                }
                g0[mt] = __builtin_amdgcn_mfma_f32_16x16x32_bf16(af.v, bw0, g0[mt], 0, 0, 0);
                g1[mt] = __builtin_amdgcn_mfma_f32_16x16x32_bf16(af.v, bw1, g1[mt], 0, 0, 0);
                g2[mt] = __builtin_amdgcn_mfma_f32_16x16x32_bf16(af.v, bw2, g2[mt], 0, 0, 0);
            }
        }
        // C/D: col=l16 -> hidden col, row=quad4+r -> window row j
#pragma unroll
        for (int mt = 0; mt < 3; mt++)
#pragma unroll
            for (int r = 0; r < 4; r++) {
                int j = mt * 16 + quad4 + r;
                if (j < NROW) {
                    grz[j * GRS + col] = pk2(g0[mt][r], g1[mt][r]);
                    gn[j * GNS + col]  = f2bf(g2[mt][r]);
                }
            }
    }

    // ---- W_hh frags -> 96 regs/wave (3 gates x 8 ks), held all 16 steps ----
    bf16x8 wf[3][8];
    {
        const ush* wp = Wr + (size_t)wave * 12288 + lane * 8;
#pragma unroll
        for (int g = 0; g < 3; g++)
#pragma unroll
            for (int ks = 0; ks < 8; ks++)
                wf[g][ks] = *(const bf16x8*)(wp + ((g * 8 + ks) << 9));
    }
    float bn = 2.f * L2E * bhh[512 + col];
    __syncthreads();  // gi + h[0] visible

    // ---- GRU loop: one barrier per step ------------------------------------
    for (int t = 0; t < K_; t++) {
        const ush* hc = &hl[t & 1][0];
        ush*       hx = &hl[(t + 1) & 1][0];
#pragma unroll
        for (int T = 0; T < 2; T++) {
            floatx4 a0 = (floatx4){0.f, 0.f, 0.f, 0.f};
            floatx4 a1 = (floatx4){0.f, 0.f, 0.f, 0.f};
            floatx4 a2 = (floatx4){bn, bn, bn, bn};
            const ush* ha = hc + (T * 16 + l16) * HS + quad * 8;
#pragma unroll
            for (int ks = 0; ks < 8; ks++) {
                bf16x8 af = *(const bf16x8*)(ha + ks * 32);
                a0 = __builtin_amdgcn_mfma_f32_16x16x32_bf16(af, wf[0][ks], a0, 0, 0, 0);
                a1 = __builtin_amdgcn_mfma_f32_16x16x32_bf16(af, wf[1][ks], a1, 0, 0, 0);
                a2 = __builtin_amdgcn_mfma_f32_16x16x32_bf16(af, wf[2][ks], a2, 0, 0, 0);
            }
#pragma unroll
            for (int r = 0; r < 4; r++) {
                int row = T * 16 + quad4 + r;
                unsigned int c = grz[(row + t) * GRS + col];
                float gv = bf2f(gn[(row + t) * GNS + col]);
                float ar = a0[r] + __uint_as_float(c << 16);
                float az = a1[r] + __uint_as_float(c & 0xffff0000u);
                float rg = rcpf(1.f + fexp2(ar));           // sigmoid(-scaled)
                float zg = rcpf(1.f + fexp2(az));
                float u  = gv + rg * a2[r];
                float ng = 1.f - 2.f * rcpf(fexp2(u) + 1.f); // tanh(2log2e-scaled)
                float ho = bf2f(hc[row * HS + col]);
                hx[row * HS + col] = f2bf(ng + zg * (ho - ng));
            }
        }
        __syncthreads();
    }
    // ---- final h (in hl[0]) -> out (fp32) ----------------------------------
#pragma unroll
    for (int T = 0; T < 2; T++)
#pragma unroll
        for (int r = 0; r < 4; r++) {
            int row = T * 16 + quad4 + r;
            out[(size_t)(p0 + row) * H_ + col] = bf2f(hl[0][row * HS + col]);
        }
}

extern "C" void kernel_launch(void* const* d_in, const int* in_sizes, int n_in,
                              void* d_out, int out_size, void* d_ws, size_t ws_size,
                              hipStream_t stream) {
    const float* x    = (const float*)d_in[0];
    const float* W_ih = (const float*)d_in[1];
    const float* W_hh = (const float*)d_in[2];
    const float* b_ih = (const float*)d_in[3];
    const float* b_hh = (const float*)d_in[4];
    float* out = (float*)d_out;

    // ws layout (bytes): Wir 393,216 | Wr 393,216  (scaled, 16-wave layout)
    char* ws = (char*)d_ws;
    ush* Wir = (ush*)ws;
    ush* Wr  = (ush*)(ws + 393216);

    wprep<<<2 * NWR / 256, 256, 0, stream>>>(W_ih, W_hh, Wir, Wr);
    rnn_fused<<<B_ * L_ / MT, 1024, 0, stream>>>(x, Wir, Wr, b_ih, b_hh, out);
}

// Round 9
// 281.432 us; speedup vs baseline: 1.0045x; 1.0045x over previous
//
#include <hip/hip_runtime.h>
#include <hip/hip_bf16.h>
#include <cstdint>

// LocalRNN: B=16 L=1024 D=256 H=256 K=16 (GRU over K-window per position).
// FP32 in/out. Round-9: r8 structure (16 waves x 16-col stripes, MT=32,
// one barrier/step) + __launch_bounds__(1024, 4): 128-reg/wave budget so the
// 96-reg wf (W_hh frags) stays register-resident at 4 waves/SIMD.
// (r8 omitted the hint -> compiler capped at 64 VGPR and spilled wf to
//  scratch: FETCH 15->123 MB, dur 141->240 us. The hint IS the fix.)

#define B_  16
#define L_  1024
#define D_  256
#define H_  256
#define K_  16
#define MT  32             // positions per block
#define NROW 47            // gi rows per block = MT + K - 1
#define HS  264            // h LDS row stride (u16)
#define GRS 258            // grz LDS row stride (u32)
#define GNS 264            // gn LDS row stride (u16)
#define L2E 1.44269504f
#define NWR 196608         // 768*256

typedef __attribute__((ext_vector_type(8))) short  bf16x8;
typedef __attribute__((ext_vector_type(4))) float  floatx4;
typedef unsigned short ush;

#if __has_builtin(__builtin_amdgcn_exp2f)
#define fexp2(x) __builtin_amdgcn_exp2f(x)
#else
#define fexp2(x) exp2f(x)
#endif

__device__ __forceinline__ float bf2f(ush u) {
    union { unsigned int i; float f; } v; v.i = ((unsigned int)u) << 16; return v.f;
}
__device__ __forceinline__ ush f2bf(float f) {
    union { float f; unsigned int i; } v; v.f = f;
    unsigned int x = v.i;
    return (ush)((x + 0x7FFFu + ((x >> 16) & 1u)) >> 16);  // RNE
}
__device__ __forceinline__ unsigned int pk2(float a, float b) {
    union { __hip_bfloat162 v; unsigned int u; } c;
    c.v = __float22bfloat162_rn(make_float2(a, b));  // lo=a, hi=b
    return c.u;
}
__device__ __forceinline__ float rcpf(float x) { return __builtin_amdgcn_rcpf(x); }

// ---- wprep: repack W_ih / W_hh into 16-wave frag layout, scale-folded ------
// element e = (w*24 + g*8 + ks)*512 + lane*8 + j ; wave w owns cols w*16..+15
__global__ __launch_bounds__(256) void wprep(const float* __restrict__ Wih,
                                             const float* __restrict__ Whh,
                                             ush* __restrict__ Wir,
                                             ush* __restrict__ Wr) {
    int idx = blockIdx.x * 256 + threadIdx.x;       // 0 .. 2*NWR-1
    const float* src = (idx < NWR) ? Whh : Wih;
    ush* dst         = (idx < NWR) ? Wr  : Wir;
    int e = (idx < NWR) ? idx : idx - NWR;
    int w  = e / 12288, r1 = e % 12288;
    int f  = r1 / 512,  r3 = r1 % 512;              // f = g*8 + ks
    int g  = f >> 3,    ks = f & 7;
    int lane = r3 >> 3, j  = r3 & 7;
    int l16 = lane & 15, quad = lane >> 4;
    int srow = g * 256 + w * 16 + l16;
    int scol = ks * 32 + quad * 8 + j;
    float scl = (g < 2) ? -L2E : 2.f * L2E;
    dst[e] = f2bf(src[srow * 256 + scol] * scl);
}

// ---- fused kernel: 512 blocks x 1024 thr, 4 waves/SIMD ---------------------
__global__ __launch_bounds__(1024, 4) void rnn_fused(const float* __restrict__ x,
                                                     const ush* __restrict__ Wir,
                                                     const ush* __restrict__ Wr,
                                                     const float* __restrict__ bih,
                                                     const float* __restrict__ bhh,
                                                     float* __restrict__ out) {
    __shared__ unsigned int grz[NROW * GRS];        // 48,504 B
    __shared__ __align__(16) ush gn[NROW * GNS];    // 24,816 B
    __shared__ __align__(16) ush hl[2][MT * HS];    // 33,792 B  (tot 107,112)

    int tid  = threadIdx.x;
    int wave = tid >> 6, lane = tid & 63;
    int l16  = lane & 15, quad = lane >> 4, quad4 = quad * 4;
    int p0   = blockIdx.x * MT;
    int bb   = p0 >> 10, lb = p0 & 1023;
    int col  = wave * 16 + l16;                     // this thread's hidden col

    // ---- zero h[0] ---------------------------------------------------------
    for (int idx = tid; idx < MT * HS / 2; idx += 1024)
        ((unsigned int*)(&hl[0][0]))[idx] = 0u;

    // ---- phase 1: gi GEMM (A direct from global x, fp32->bf16 in regs) -----
    {
        floatx4 g0[3], g1[3], g2[3];                // [mt], gates r,z,n
        float br = -L2E * (bih[col] + bhh[col]);
        float bz = -L2E * (bih[256 + col] + bhh[256 + col]);
        float bn_ = 2.f * L2E * bih[512 + col];
#pragma unroll
        for (int mt = 0; mt < 3; mt++) {
            g0[mt] = (floatx4){br, br, br, br};
            g1[mt] = (floatx4){bz, bz, bz, bz};
            g2[mt] = (floatx4){bn_, bn_, bn_, bn_};
        }
        const float* xrow[3];
        bool vld[3];
#pragma unroll
        for (int mt = 0; mt < 3; mt++) {
            int tok = lb - 15 + mt * 16 + l16;
            vld[mt]  = (unsigned)tok < (unsigned)L_;
            xrow[mt] = x + ((size_t)((bb << 10) + (vld[mt] ? tok : 0))) * D_ + quad * 8;
        }
        const ush* wp = Wir + (size_t)wave * 12288 + lane * 8;
#pragma unroll
        for (int ks = 0; ks < 8; ks++) {
            bf16x8 bw0 = *(const bf16x8*)(wp + ((0 * 8 + ks) << 9));
            bf16x8 bw1 = *(const bf16x8*)(wp + ((1 * 8 + ks) << 9));
            bf16x8 bw2 = *(const bf16x8*)(wp + ((2 * 8 + ks) << 9));
#pragma unroll
            for (int mt = 0; mt < 3; mt++) {
                union { uint4 u; bf16x8 v; } af;
                if (vld[mt]) {
                    float4 a0 = *(const float4*)(xrow[mt] + ks * 32);
                    float4 a1 = *(const float4*)(xrow[mt] + ks * 32 + 4);
                    af.u = make_uint4(pk2(a0.x, a0.y), pk2(a0.z, a0.w),
                                      pk2(a1.x, a1.y), pk2(a1.z, a1.w));
                } else {
                    af.u = make_uint4(0u, 0u, 0u, 0u);
                }
                g0[mt] = __builtin_amdgcn_mfma_f32_16x16x32_bf16(af.v, bw0, g0[mt], 0, 0, 0);
                g1[mt] = __builtin_amdgcn_mfma_f32_16x16x32_bf16(af.v, bw1, g1[mt], 0, 0, 0);
                g2[mt] = __builtin_amdgcn_mfma_f32_16x16x32_bf16(af.v, bw2, g2[mt], 0, 0, 0);
            }
        }
        // C/D: col=l16 -> hidden col, row=quad4+r -> window row j
#pragma unroll
        for (int mt = 0; mt < 3; mt++)
#pragma unroll
            for (int r = 0; r < 4; r++) {
                int j = mt * 16 + quad4 + r;
                if (j < NROW) {
                    grz[j * GRS + col] = pk2(g0[mt][r], g1[mt][r]);
                    gn[j * GNS + col]  = f2bf(g2[mt][r]);
                }
            }
    }

    // ---- W_hh frags -> 96 regs/wave (3 gates x 8 ks), held all 16 steps ----
    bf16x8 wf[3][8];
    {
        const ush* wp = Wr + (size_t)wave * 12288 + lane * 8;
#pragma unroll
        for (int g = 0; g < 3; g++)
#pragma unroll
            for (int ks = 0; ks < 8; ks++)
                wf[g][ks] = *(const bf16x8*)(wp + ((g * 8 + ks) << 9));
    }
    float bn = 2.f * L2E * bhh[512 + col];
    __syncthreads();  // gi + h[0] visible

    // ---- GRU loop: one barrier per step ------------------------------------
    for (int t = 0; t < K_; t++) {
        const ush* hc = &hl[t & 1][0];
        ush*       hx = &hl[(t + 1) & 1][0];
#pragma unroll
        for (int T = 0; T < 2; T++) {
            floatx4 a0 = (floatx4){0.f, 0.f, 0.f, 0.f};
            floatx4 a1 = (floatx4){0.f, 0.f, 0.f, 0.f};
            floatx4 a2 = (floatx4){bn, bn, bn, bn};
            const ush* ha = hc + (T * 16 + l16) * HS + quad * 8;
#pragma unroll
            for (int ks = 0; ks < 8; ks++) {
                bf16x8 af = *(const bf16x8*)(ha + ks * 32);
                a0 = __builtin_amdgcn_mfma_f32_16x16x32_bf16(af, wf[0][ks], a0, 0, 0, 0);
                a1 = __builtin_amdgcn_mfma_f32_16x16x32_bf16(af, wf[1][ks], a1, 0, 0, 0);
                a2 = __builtin_amdgcn_mfma_f32_16x16x32_bf16(af, wf[2][ks], a2, 0, 0, 0);
            }
#pragma unroll
            for (int r = 0; r < 4; r++) {
                int row = T * 16 + quad4 + r;
                unsigned int c = grz[(row + t) * GRS + col];
                float gv = bf2f(gn[(row + t) * GNS + col]);
                float ar = a0[r] + __uint_as_float(c << 16);
                float az = a1[r] + __uint_as_float(c & 0xffff0000u);
                float rg = rcpf(1.f + fexp2(ar));           // sigmoid(-scaled)
                float zg = rcpf(1.f + fexp2(az));
                float u  = gv + rg * a2[r];
                float ng = 1.f - 2.f * rcpf(fexp2(u) + 1.f); // tanh(2log2e-scaled)
                float ho = bf2f(hc[row * HS + col]);
                hx[row * HS + col] = f2bf(ng + zg * (ho - ng));
            }
        }
        __syncthreads();
    }
    // ---- final h (in hl[0]) -> out (fp32) ----------------------------------
#pragma unroll
    for (int T = 0; T < 2; T++)
#pragma unroll
        for (int r = 0; r < 4; r++) {
            int row = T * 16 + quad4 + r;
            out[(size_t)(p0 + row) * H_ + col] = bf2f(hl[0][row * HS + col]);
        }
}

extern "C" void kernel_launch(void* const* d_in, const int* in_sizes, int n_in,
                              void* d_out, int out_size, void* d_ws, size_t ws_size,
                              hipStream_t stream) {
    const float* x    = (const float*)d_in[0];
    const float* W_ih = (const float*)d_in[1];
    const float* W_hh = (const float*)d_in[2];
    const float* b_ih = (const float*)d_in[3];
    const float* b_hh = (const float*)d_in[4];
    float* out = (float*)d_out;

    // ws layout (bytes): Wir 393,216 | Wr 393,216  (scaled, 16-wave layout)
    char* ws = (char*)d_ws;
    ush* Wir = (ush*)ws;
    ush* Wr  = (ush*)(ws + 393216);

    wprep<<<2 * NWR / 256, 256, 0, stream>>>(W_ih, W_hh, Wir, Wr);
    rnn_fused<<<B_ * L_ / MT, 1024, 0, stream>>>(x, Wir, Wr, b_ih, b_hh, out);
}